// Round 3
// baseline (152.544 us; speedup 1.0000x reference)
//
#include <hip/hip_runtime.h>

#define EPS 1e-7f
#define BATCH 8
#define NPT 2048   // points per batch
#define NFEAT 6
#define LOG2E 1.44269504088896340736f

typedef float vf4 __attribute__((ext_vector_type(4)));  // native vec for nontemporal store

// ws layout (floats): pow[BATCH*NPT] | cb[BATCH] | beff2
// cb[b] = beta^2*1e-4*LOG2E / (d_min_b * (r^2+EPS));  beff2 = beta^2*1e-4*LOG2E
#define WS_POW   0
#define WS_CB    (BATCH * NPT)
#define WS_BEFF2 (BATCH * NPT + BATCH)

__global__ __launch_bounds__(256)
void precompute_kernel(const float* __restrict__ emb,
                       const float* __restrict__ alpha,
                       const float* __restrict__ beta,
                       const float* __restrict__ radius,
                       float* __restrict__ ws) {
    int b = blockIdx.x;
    int tid = threadIdx.x;
    float a2 = 2.0f * alpha[0];
    const float* mom = emb + (size_t)b * NFEAT * NPT + 4 * NPT;
    float* powp = ws + WS_POW + (size_t)b * NPT;

    float local_min = 3.0e38f;
    for (int n = tid; n < NPT; n += 256) {
        float m = mom[n];
        float p = __expf(a2 * __logf(m));   // momentum^(2*alpha)
        powp[n] = p;
        local_min = fminf(local_min, p);
    }
    // wave (64-lane) shuffle reduce, then LDS across 4 waves
    for (int off = 32; off > 0; off >>= 1)
        local_min = fminf(local_min, __shfl_down(local_min, off, 64));
    __shared__ float smin[4];
    int wave = tid >> 6;
    if ((tid & 63) == 0) smin[wave] = local_min;
    __syncthreads();
    if (tid == 0) {
        float dmin = fminf(fminf(smin[0], smin[1]), fminf(smin[2], smin[3])) + EPS;
        float r  = radius[0];
        float bt = beta[0];
        float beff2 = bt * bt * 1e-4f * LOG2E;      // beta^2/1e4, pre-scaled to base-2
        ws[WS_CB + b] = beff2 / (dmin * (r * r + EPS));
        if (b == 0) ws[WS_BEFF2] = beff2;
    }
}

// Each block: R=8 consecutive rows of one batch; 512 threads x float4 = 2048 cols.
// Column fragments (cx, cy, pw) and all scalars are loaded once, reused 8x.
#define RPB 8
__global__ __launch_bounds__(512)
void wij_kernel(const float* __restrict__ emb,
                const float* __restrict__ ws,
                float* __restrict__ out) {
    int blk = blockIdx.x;                      // 0 .. BATCH*NPT/RPB - 1
    int b  = blk / (NPT / RPB);                // 256 blocks per batch
    int n0 = (blk % (NPT / RPB)) * RPB;

    const float* base = emb + (size_t)b * NFEAT * NPT;
    const float* powp = ws + WS_POW + (size_t)b * NPT;
    float cb    = ws[WS_CB + b];
    float beff2 = ws[WS_BEFF2];

    int t = threadIdx.x;
    vf4 cx = ((const vf4*)(base + 1 * NPT))[t];
    vf4 cy = ((const vf4*)(base + 2 * NPT))[t];
    vf4 pw = ((const vf4*)powp)[t];

    // hoist row scalars
    float xn[RPB], yn[RPB], pn[RPB];
    #pragma unroll
    for (int r = 0; r < RPB; ++r) {
        xn[r] = base[1 * NPT + n0 + r];
        yn[r] = base[2 * NPT + n0 + r];
        pn[r] = powp[n0 + r];
    }

    vf4* outp = (vf4*)(out + (size_t)(b * NPT + n0) * NPT) + t;
    #pragma unroll
    for (int r = 0; r < RPB; ++r) {
        vf4 w;
        {
            float dx = xn[r] - cx.x, dy = yn[r] - cy.x;
            float da = (dx * dx + dy * dy) * fminf(pn[r], pw.x);
            w.x = __builtin_amdgcn_exp2f(beff2 - cb * da);
        }
        {
            float dx = xn[r] - cx.y, dy = yn[r] - cy.y;
            float da = (dx * dx + dy * dy) * fminf(pn[r], pw.y);
            w.y = __builtin_amdgcn_exp2f(beff2 - cb * da);
        }
        {
            float dx = xn[r] - cx.z, dy = yn[r] - cy.z;
            float da = (dx * dx + dy * dy) * fminf(pn[r], pw.z);
            w.z = __builtin_amdgcn_exp2f(beff2 - cb * da);
        }
        {
            float dx = xn[r] - cx.w, dy = yn[r] - cy.w;
            float da = (dx * dx + dy * dy) * fminf(pn[r], pw.w);
            w.w = __builtin_amdgcn_exp2f(beff2 - cb * da);
        }
        __builtin_nontemporal_store(w, outp + (size_t)r * (NPT / 4));
    }
}

extern "C" void kernel_launch(void* const* d_in, const int* in_sizes, int n_in,
                              void* d_out, int out_size, void* d_ws, size_t ws_size,
                              hipStream_t stream) {
    const float* emb    = (const float*)d_in[0];
    const float* alpha  = (const float*)d_in[1];
    const float* beta   = (const float*)d_in[2];
    const float* radius = (const float*)d_in[3];
    float* out = (float*)d_out;
    float* ws  = (float*)d_ws;

    precompute_kernel<<<BATCH, 256, 0, stream>>>(emb, alpha, beta, radius, ws);
    wij_kernel<<<(BATCH * NPT) / RPB, 512, 0, stream>>>(emb, ws, out);
}

// Round 4
// 146.361 us; speedup vs baseline: 1.0423x; 1.0423x over previous
//
#include <hip/hip_runtime.h>

#define EPS 1e-7f
#define BATCH 8
#define NPT 2048   // points per batch
#define NFEAT 6
#define LOG2E 1.44269504088896340736f
#define RPB 8      // rows per block

typedef float vf4 __attribute__((ext_vector_type(4)));  // native vec for nontemporal store

// Single fused kernel. Each block handles RPB consecutive rows (b, n0..n0+7).
// Every block loads ALL 2048 columns of its batch anyway, so it redundantly
// computes pow = momentum^(2*alpha) for the whole batch (4 values/thread),
// stages it in LDS, and block-reduces the batch min — no precompute kernel,
// no workspace, no inter-kernel dependency.
__global__ __launch_bounds__(512)
void wij_fused_kernel(const float* __restrict__ emb,
                      const float* __restrict__ alpha,
                      const float* __restrict__ beta,
                      const float* __restrict__ radius,
                      float* __restrict__ out) {
    __shared__ float spow[NPT];   // pow row for this batch
    __shared__ float sred[8];     // per-wave mins

    int blk = blockIdx.x;                      // 0 .. BATCH*NPT/RPB - 1
    int b  = blk >> 8;                         // / (NPT/RPB) = /256
    int n0 = (blk & 255) * RPB;

    const float* base = emb + (size_t)b * NFEAT * NPT;
    int t = threadIdx.x;

    // ---- pow + min (redundant per block, trivial cost) ----
    float a2 = 2.0f * alpha[0];
    vf4 pm = ((const vf4*)(base + 4 * NPT))[t];
    vf4 pw;
    pw.x = __builtin_amdgcn_exp2f(a2 * __log2f(pm.x));
    pw.y = __builtin_amdgcn_exp2f(a2 * __log2f(pm.y));
    pw.z = __builtin_amdgcn_exp2f(a2 * __log2f(pm.z));
    pw.w = __builtin_amdgcn_exp2f(a2 * __log2f(pm.w));
    ((vf4*)spow)[t] = pw;

    float lmin = fminf(fminf(pw.x, pw.y), fminf(pw.z, pw.w));
    for (int off = 32; off > 0; off >>= 1)
        lmin = fminf(lmin, __shfl_down(lmin, off, 64));
    if ((t & 63) == 0) sred[t >> 6] = lmin;
    __syncthreads();
    float dmin = fminf(fminf(fminf(sred[0], sred[1]), fminf(sred[2], sred[3])),
                       fminf(fminf(sred[4], sred[5]), fminf(sred[6], sred[7]))) + EPS;

    // ---- fold scalars: w = exp2(beff2 - cb * |c_n-c_m|^2 * min(pn,pm)) ----
    float r  = radius[0];
    float bt = beta[0];
    float beff2 = bt * bt * 1e-4f * LOG2E;           // beta^2/1e4 in base-2
    float cb = beff2 / (dmin * (r * r + EPS));       // one divide per thread, off hot path

    // ---- column fragments ----
    vf4 cx = ((const vf4*)(base + 1 * NPT))[t];
    vf4 cy = ((const vf4*)(base + 2 * NPT))[t];

    // ---- row scalars ----
    float xn[RPB], yn[RPB], pn[RPB];
    #pragma unroll
    for (int rI = 0; rI < RPB; ++rI) {
        xn[rI] = base[1 * NPT + n0 + rI];
        yn[rI] = base[2 * NPT + n0 + rI];
        pn[rI] = spow[n0 + rI];
    }

    vf4* outp = (vf4*)(out + (size_t)(b * NPT + n0) * NPT) + t;
    #pragma unroll
    for (int rI = 0; rI < RPB; ++rI) {
        vf4 w;
        {
            float dx = xn[rI] - cx.x, dy = yn[rI] - cy.x;
            float da = (dx * dx + dy * dy) * fminf(pn[rI], pw.x);
            w.x = __builtin_amdgcn_exp2f(beff2 - cb * da);
        }
        {
            float dx = xn[rI] - cx.y, dy = yn[rI] - cy.y;
            float da = (dx * dx + dy * dy) * fminf(pn[rI], pw.y);
            w.y = __builtin_amdgcn_exp2f(beff2 - cb * da);
        }
        {
            float dx = xn[rI] - cx.z, dy = yn[rI] - cy.z;
            float da = (dx * dx + dy * dy) * fminf(pn[rI], pw.z);
            w.z = __builtin_amdgcn_exp2f(beff2 - cb * da);
        }
        {
            float dx = xn[rI] - cx.w, dy = yn[rI] - cy.w;
            float da = (dx * dx + dy * dy) * fminf(pn[rI], pw.w);
            w.w = __builtin_amdgcn_exp2f(beff2 - cb * da);
        }
        __builtin_nontemporal_store(w, outp + (size_t)rI * (NPT / 4));
    }
}

extern "C" void kernel_launch(void* const* d_in, const int* in_sizes, int n_in,
                              void* d_out, int out_size, void* d_ws, size_t ws_size,
                              hipStream_t stream) {
    const float* emb    = (const float*)d_in[0];
    const float* alpha  = (const float*)d_in[1];
    const float* beta   = (const float*)d_in[2];
    const float* radius = (const float*)d_in[3];
    float* out = (float*)d_out;
    (void)d_ws; (void)ws_size;

    wij_fused_kernel<<<(BATCH * NPT) / RPB, 512, 0, stream>>>(emb, alpha, beta, radius, out);
}